// Round 3
// baseline (360.538 us; speedup 1.0000x reference)
//
#include <hip/hip_runtime.h>

// SimpleRetention R3: B=131072 batches of 14x14 fp32, 4 sequential 7x7
// chunks with carried state r.
//  - 64-thread (1-wave) blocks, grid B/64 = 2048 -> 8 blocks/CU, ALL
//    co-resident (no tail round), barriers ~free.
//  - Inputs: direct per-thread global loads (compile-time imm offsets from
//    one base), double-buffered 1 chunk ahead so compute hides latency.
//  - Outputs: per-chunk LDS staging (64x50 floats = 12.8KB) + coalesced
//    store loop with incremental index math (no divides).
// Requires B % 64 == 0 (true: 131072).

#define CS 7
#define NT 64
#define OSTR 50   // LDS floats per batch (49 + 1 pad -> 2-way banks, free)

template <int C>
__device__ __forceinline__ void load_chunk(const float* __restrict__ xb,
                                           float x[49]) {
    constexpr int off = (C >> 1) * CS * 14 + (C & 1) * CS;
#pragma unroll
    for (int e = 0; e < 49; e++)
        x[e] = xb[off + (e / 7) * 14 + (e % 7)];   // folds to imm offsets
}

template <int C>
__device__ __forceinline__ void process_chunk(
    const float x[49], float r[49],
    const float* __restrict__ WQ, const float* __restrict__ WK,
    const float* __restrict__ WV, const float* __restrict__ Dm,
    float* __restrict__ outb, float* __restrict__ olds, int tid) {
    constexpr int ro = (C >> 1) * CS, co = (C & 1) * CS;
    const float* wq = WQ + C * 49;   // uniform -> s_load
    const float* wk = WK + C * 49;
    const float* wv = WV + C * 49;

    // K = x @ Wk, V = x @ Wv (fused over shared x reads)
    float K[49], V[49];
#pragma unroll
    for (int j = 0; j < CS; j++) {
        float wck[CS], wcv[CS];
#pragma unroll
        for (int k = 0; k < CS; k++) {
            wck[k] = wk[k * CS + j];
            wcv[k] = wv[k * CS + j];
        }
#pragma unroll
        for (int i = 0; i < CS; i++) {
            float ak = 0.f, av = 0.f;
#pragma unroll
            for (int k = 0; k < CS; k++) {
                ak = fmaf(x[i * CS + k], wck[k], ak);
                av = fmaf(x[i * CS + k], wcv[k], av);
            }
            K[i * CS + j] = ak;
            V[i * CS + j] = av;
        }
    }

    // per output row d: q -> s -> cross(r_prev) -> o -> LDS
#pragma unroll
    for (int d = 0; d < CS; d++) {
        const float ev = (d == 0) ? 0.2f : (d == 1) ? 0.04f : (d == 2) ? 0.008f
                        : (d == 3) ? 0.0016f : (d == 4) ? 3.2e-4f
                        : (d == 5) ? 6.4e-5f : 1.28e-5f;
        float q[CS];
#pragma unroll
        for (int j = 0; j < CS; j++) {
            float a = 0.f;
#pragma unroll
            for (int k = 0; k < CS; k++)
                a = fmaf(x[d * CS + k], wq[k * CS + j], a);
            q[j] = a;
        }
        float s[CS];
#pragma unroll
        for (int k = 0; k < CS; k++) {
            float a = 0.f;
#pragma unroll
            for (int j = 0; j < CS; j++) a = fmaf(q[j], K[k * CS + j], a);
            s[k] = a * Dm[(ro + d) * 14 + co + k];   // uniform -> s_load
        }
        float o[CS];
#pragma unroll
        for (int v = 0; v < CS; v++) {
            float a = 0.f;
#pragma unroll
            for (int j = 0; j < CS; j++) a = fmaf(q[j], r[j * CS + v], a);
            o[v] = ev * a;
        }
#pragma unroll
        for (int k = 0; k < CS; k++)
#pragma unroll
            for (int v = 0; v < CS; v++)
                o[v] = fmaf(s[k], V[k * CS + v], o[v]);
#pragma unroll
        for (int v = 0; v < CS; v++)
            olds[tid * OSTR + d * CS + v] = o[v];
    }

    __syncthreads();   // 1-wave block: ~free (waitcnt + trivial barrier)

    // coalesced store: iteration (s, rr) covers element (rr, cc) of batch bl,
    // idx = s*64 + tid, bl = idx/7, cc = idx%7, maintained incrementally.
    {
        int bl = tid / 7;           // one magic-mul div
        int cc = tid - bl * 7;
        int gw = bl * 196 + cc;     // word offset in block's out region
        int lw = bl * OSTR + cc;    // word offset in LDS
#pragma unroll
        for (int s = 0; s < 7; s++) {
#pragma unroll
            for (int rr = 0; rr < CS; rr++)
                outb[gw + (ro + rr) * 14 + co] = olds[lw + rr * CS];
            if (s < 6) {            // idx += 64: bl += 9, cc += 1 (+carry)
                cc += 1; gw += 1765; lw += 451;
                int cy = cc >= 7;
                cc = cy ? cc - 7 : cc;
                gw = cy ? gw + 189 : gw;
                lw = cy ? lw + 43 : lw;
            }
        }
    }

    __syncthreads();   // LDS reads done before next chunk's o overwrites

    // r += K^T V (pure VALU tail, overlaps store drain)
#pragma unroll
    for (int dd = 0; dd < CS; dd++)
#pragma unroll
        for (int v = 0; v < CS; v++) {
            float a = r[dd * CS + v];
#pragma unroll
            for (int k = 0; k < CS; k++)
                a = fmaf(K[k * CS + dd], V[k * CS + v], a);
            r[dd * CS + v] = a;
        }
}

__global__ __launch_bounds__(NT, 2) void retention_kernel(
    const float* __restrict__ X, const float* __restrict__ WQ,
    const float* __restrict__ WK, const float* __restrict__ WV,
    const float* __restrict__ Dm, float* __restrict__ Out, int B) {
    __shared__ float olds[NT * OSTR];   // 12800 B -> 8+ blocks/CU
    const int tid = threadIdx.x;
    const int bbase = blockIdx.x * NT;
    const float* xb = X + (size_t)(bbase + tid) * 196;
    float* outb = Out + (size_t)bbase * 196;

    float r[49];
#pragma unroll
    for (int i = 0; i < 49; i++) r[i] = 0.f;

    float xa[49], xc[49];
    load_chunk<0>(xb, xa);
    load_chunk<1>(xb, xc);    // prefetch: in flight under chunk-0 compute
    process_chunk<0>(xa, r, WQ, WK, WV, Dm, outb, olds, tid);
    load_chunk<2>(xb, xa);
    process_chunk<1>(xc, r, WQ, WK, WV, Dm, outb, olds, tid);
    load_chunk<3>(xb, xc);
    process_chunk<2>(xa, r, WQ, WK, WV, Dm, outb, olds, tid);
    process_chunk<3>(xc, r, WQ, WK, WV, Dm, outb, olds, tid);
}

extern "C" void kernel_launch(void* const* d_in, const int* in_sizes, int n_in,
                              void* d_out, int out_size, void* d_ws, size_t ws_size,
                              hipStream_t stream) {
    const float* X  = (const float*)d_in[0];
    const float* WQ = (const float*)d_in[1];
    const float* WK = (const float*)d_in[2];
    const float* WV = (const float*)d_in[3];
    const float* Dm = (const float*)d_in[4];
    float* Out = (float*)d_out;

    int B = in_sizes[0] / 196;     // 131072, divisible by 64
    int grid = B / NT;
    retention_kernel<<<grid, NT, 0, stream>>>(X, WQ, WK, WV, Dm, Out, B);
}

// Round 4
// 298.757 us; speedup vs baseline: 1.2068x; 1.2068x over previous
//
#include <hip/hip_runtime.h>

// SimpleRetention R4: B=131072 batches of 14x14 fp32, 4 sequential 7x7
// chunks with carried state r.
//  - 1-wave (64-thread) blocks, 1 batch/thread, grid 2048 -> 8 blocks/CU all
//    resident (VGPR<=256); phases drift across 8 waves/CU -> TLP hides HBM.
//  - Input: direct scalar loads per chunk (L3 absorbs the ~2x re-read).
//  - Output: chunk-A rows staged in 12.75KB LDS; chunk-B completes each
//    14-float row and stores it DENSE (7x float2) -> rows tile the 784B
//    batch region contiguously within ~1K cycles -> L2 merges -> ~1x write.

#define CS 7
#define NT 64
#define OSTR 51   // LDS words/batch; 51 mod 32 = 19 (odd-ish) -> conflict-free

template <int CC>  // CC: 0 = left chunk (cols 0-6), 1 = right (cols 7-13)
__device__ __forceinline__ void process_chunk(
    int h, const float* __restrict__ xb, float* __restrict__ ob,
    const float* __restrict__ WQ, const float* __restrict__ WK,
    const float* __restrict__ WV, const float* __restrict__ Dm,
    float r[49], float* __restrict__ os, int tid)
{
    const int c = 2 * h + CC;
    const float* wq = WQ + c * 49;   // wave-uniform -> s_load
    const float* wk = WK + c * 49;
    const float* wv = WV + c * 49;
    const int xoff = h * 98 + CC * CS;

    // ---- x chunk: 49 direct scalar loads (independent -> deep MLP)
    float x[49];
#pragma unroll
    for (int i = 0; i < CS; i++)
#pragma unroll
        for (int j = 0; j < CS; j++)
            x[i * CS + j] = xb[xoff + i * 14 + j];

    // ---- K = x @ Wk, V = x @ Wv (shared x reads)
    float K[49], V[49];
#pragma unroll
    for (int j = 0; j < CS; j++) {
        float wck[CS], wcv[CS];
#pragma unroll
        for (int k = 0; k < CS; k++) {
            wck[k] = wk[k * CS + j];
            wcv[k] = wv[k * CS + j];
        }
#pragma unroll
        for (int i = 0; i < CS; i++) {
            float ak = 0.f, av = 0.f;
#pragma unroll
            for (int k = 0; k < CS; k++) {
                ak = fmaf(x[i * CS + k], wck[k], ak);
                av = fmaf(x[i * CS + k], wcv[k], av);
            }
            K[i * CS + j] = ak;
            V[i * CS + j] = av;
        }
    }

    // ---- per output row d
#pragma unroll
    for (int d = 0; d < CS; d++) {
        const float ev = (d == 0) ? 0.2f : (d == 1) ? 0.04f : (d == 2) ? 0.008f
                        : (d == 3) ? 0.0016f : (d == 4) ? 3.2e-4f
                        : (d == 5) ? 6.4e-5f : 1.28e-5f;
        float q[CS];
#pragma unroll
        for (int j = 0; j < CS; j++) {
            float a = 0.f;
#pragma unroll
            for (int k = 0; k < CS; k++)
                a = fmaf(x[d * CS + k], wq[k * CS + j], a);
            q[j] = a;
        }
        float s[CS];
#pragma unroll
        for (int k = 0; k < CS; k++) {
            float a = 0.f;
#pragma unroll
            for (int j = 0; j < CS; j++) a = fmaf(q[j], K[k * CS + j], a);
            s[k] = a * Dm[(h * CS + d) * 14 + CC * CS + k];  // uniform
        }
        float o[CS];
#pragma unroll
        for (int v = 0; v < CS; v++) {
            float a = 0.f;
#pragma unroll
            for (int j = 0; j < CS; j++) a = fmaf(q[j], r[j * CS + v], a);
            o[v] = ev * a;
        }
#pragma unroll
        for (int k = 0; k < CS; k++)
#pragma unroll
            for (int v = 0; v < CS; v++)
                o[v] = fmaf(s[k], V[k * CS + v], o[v]);

        if (CC == 0) {
            // left chunk: park row in LDS (same-wave dep -> lgkmcnt only)
#pragma unroll
            for (int v = 0; v < CS; v++)
                os[tid * OSTR + d * CS + v] = o[v];
        } else {
            // right chunk: complete the 14-float row and store DENSE
            float row[14];
#pragma unroll
            for (int v = 0; v < CS; v++) row[v] = os[tid * OSTR + d * CS + v];
#pragma unroll
            for (int v = 0; v < CS; v++) row[7 + v] = o[v];
#pragma unroll
            for (int w = 0; w < 7; w++) {
                float2 p = make_float2(row[2 * w], row[2 * w + 1]);
                *reinterpret_cast<float2*>(ob + h * 98 + d * 14 + 2 * w) = p;
            }
        }
    }

    // ---- r += K^T V
#pragma unroll
    for (int dd = 0; dd < CS; dd++)
#pragma unroll
        for (int v = 0; v < CS; v++) {
            float a = r[dd * CS + v];
#pragma unroll
            for (int k = 0; k < CS; k++)
                a = fmaf(K[k * CS + dd], V[k * CS + v], a);
            r[dd * CS + v] = a;
        }
}

__global__ __launch_bounds__(NT, 2) void retention_kernel(
    const float* __restrict__ X, const float* __restrict__ WQ,
    const float* __restrict__ WK, const float* __restrict__ WV,
    const float* __restrict__ Dm, float* __restrict__ Out, int B)
{
    __shared__ float os[NT * OSTR];   // 13056 B -> LDS not the occupancy cap
    const int tid = threadIdx.x;
    const int b = blockIdx.x * NT + tid;
    const float* xb = X + (size_t)b * 196;
    float* ob = Out + (size_t)b * 196;

    float r[49];
#pragma unroll
    for (int i = 0; i < 49; i++) r[i] = 0.f;

    for (int h = 0; h < 2; ++h) {
        process_chunk<0>(h, xb, ob, WQ, WK, WV, Dm, r, os, tid);
        process_chunk<1>(h, xb, ob, WQ, WK, WV, Dm, r, os, tid);
    }
}

extern "C" void kernel_launch(void* const* d_in, const int* in_sizes, int n_in,
                              void* d_out, int out_size, void* d_ws, size_t ws_size,
                              hipStream_t stream) {
    const float* X  = (const float*)d_in[0];
    const float* WQ = (const float*)d_in[1];
    const float* WK = (const float*)d_in[2];
    const float* WV = (const float*)d_in[3];
    const float* Dm = (const float*)d_in[4];
    float* Out = (float*)d_out;

    int B = in_sizes[0] / 196;     // 131072, divisible by 64
    int grid = B / NT;
    retention_kernel<<<grid, NT, 0, stream>>>(X, WQ, WK, WV, Dm, Out, B);
}